// Round 2
// baseline (185.774 us; speedup 1.0000x reference)
//
#include <hip/hip_runtime.h>
#include <hip/hip_fp16.h>

typedef unsigned int u32;
typedef unsigned short u16;
typedef _Float16 f16x8 __attribute__((ext_vector_type(8)));
typedef float f32x4 __attribute__((ext_vector_type(4)));

#define OUT_F 8192
#define IN_F 8192
#define TOKENS 256
#define N_GROUPS 524288
#define SPLITK 8
#define KSPAN (IN_F / SPLITK)   // 1024 weights (== bytes of wq per row-split)
#define KT (KSPAN / 64)         // 16 K-iterations

// workspace layout
#define XB_OFF 0
#define T_OFF ((size_t)TOKENS * IN_F * 2)                 // 4 MiB
#define NF_OFF (T_OFF + 65536)
#define PART_OFF (NF_OFF + (size_t)N_GROUPS * 2)          // +1 MiB
#define PART_BYTES ((size_t)SPLITK * TOKENS * OUT_F * 4)  // 64 MiB
#define WS_NEED (PART_OFF + PART_BYTES)

// direct global -> LDS DMA, 16B per lane. LDS dest must be lane-linear
// (wave-uniform base + lane*16) -- our A chunk slots are exactly tid-linear,
// swizzle is applied on the GLOBAL source address (m173 pattern).
#define GLOAD16(g, l)                                                        \
  __builtin_amdgcn_global_load_lds(                                          \
      (const __attribute__((address_space(1))) void*)(g),                    \
      (__attribute__((address_space(3))) void*)(l), 16, 0, 0)

// packed f16 multiply on bit-pattern: 4 weights dequant = 1 LUT read + 2 of these
__device__ __forceinline__ u32 hm2(u32 a, __half2 s) {
  return __builtin_bit_cast(u32, __hmul2(__builtin_bit_cast(__half2, a), s));
}

// ---------------------------------------------------------------------------
// prep: fused normcvt + prep1.
// blocks [0,512): weight_norm dtype auto-detect (f16/bf16/f32 vote) -> f16 nf.
// blocks [512,1024): per (token, k-half): x -> f16 xb, partial t = x . lora_a^T.
// ---------------------------------------------------------------------------
__global__ __launch_bounds__(256) void prep(const void* __restrict__ wn,
                                            __half* __restrict__ nf,
                                            const float* __restrict__ x,
                                            const float* __restrict__ la,
                                            u16* __restrict__ xb,
                                            float* __restrict__ t) {
  int tid = threadIdx.x;
  if (blockIdx.x < 512) {
    __shared__ int votes[3];
    if (tid < 3) votes[tid] = 0;
    __syncthreads();
    const u16* pu = (const u16*)wn;
    const u32* pw = (const u32*)wn;
    int v16 = 0, vbf = 0, vf = 0;
    for (int i = tid; i < 2048; i += 256) {
      u16 u = pu[i];
      float h = __half2float(__builtin_bit_cast(__half, u));
      float b = __builtin_bit_cast(float, ((u32)u) << 16);
      if (h > 0.008f && h < 1.002f) v16++;
      if (b > 0.008f && b < 1.002f) vbf++;
    }
    for (int i = tid; i < 1024; i += 256) {
      float f = __builtin_bit_cast(float, pw[i]);
      if (f > 0.008f && f < 1.002f) vf++;
    }
    atomicAdd(&votes[0], v16);
    atomicAdd(&votes[1], vbf);
    atomicAdd(&votes[2], vf);
    __syncthreads();
    int a16 = votes[0], abf = votes[1], af32 = 2 * votes[2];
    int mode = (a16 >= abf && a16 >= af32) ? 0 : (abf >= af32 ? 1 : 2);
#pragma unroll
    for (int i = 0; i < 4; ++i) {
      int g = blockIdx.x * 1024 + i * 256 + tid;
      float v;
      if (mode == 0) v = __half2float(((const __half*)wn)[g]);
      else if (mode == 1) v = __builtin_bit_cast(float, ((u32)((const u16*)wn)[g]) << 16);
      else v = ((const float*)wn)[g];
      nf[g] = __float2half(v);
    }
    return;
  }
  int b2 = blockIdx.x - 512;
  int m = b2 & 255;
  int half = b2 >> 8;
  const float4* xr = (const float4*)(x + (size_t)m * IN_F);
  u32* xbr = (u32*)(xb + (size_t)m * IN_F);
  float pl[16];
#pragma unroll
  for (int r = 0; r < 16; ++r) pl[r] = 0.f;
#pragma unroll
  for (int it = 0; it < 4; ++it) {
    int k4 = half * 1024 + it * 256 + tid;
    float4 xv = xr[k4];
    u32 p0 = __builtin_bit_cast(u32, __float22half2_rn(make_float2(xv.x, xv.y)));
    u32 p1 = __builtin_bit_cast(u32, __float22half2_rn(make_float2(xv.z, xv.w)));
    ((uint2*)xbr)[k4] = make_uint2(p0, p1);
#pragma unroll
    for (int r = 0; r < 16; ++r) {
      const float4 av = ((const float4*)(la + (size_t)r * IN_F))[k4];
      pl[r] = fmaf(xv.x, av.x, pl[r]);
      pl[r] = fmaf(xv.y, av.y, pl[r]);
      pl[r] = fmaf(xv.z, av.z, pl[r]);
      pl[r] = fmaf(xv.w, av.w, pl[r]);
    }
  }
#pragma unroll
  for (int r = 0; r < 16; ++r) {
    float v = pl[r];
#pragma unroll
    for (int d = 32; d > 0; d >>= 1) v += __shfl_xor(v, d);
    pl[r] = v;
  }
  __shared__ float red[4][16];
  int wave = tid >> 6, lane = tid & 63;
  if (lane == 0) {
#pragma unroll
    for (int r = 0; r < 16; ++r) red[wave][r] = pl[r];
  }
  __syncthreads();
  if (tid < 16)
    t[((size_t)half * TOKENS + m) * 16 + tid] =
        red[0][tid] + red[1][tid] + red[2][tid] + red[3][tid];
}

// ---------------------------------------------------------------------------
// prep2 (fallback path only): d_out = bias + lora (atomic reduction target).
// ---------------------------------------------------------------------------
__global__ __launch_bounds__(256) void prep2(const float* __restrict__ t,
                                             const float* __restrict__ lb,
                                             const float* __restrict__ bias,
                                             float* __restrict__ out) {
  __shared__ float tS[16 * 16];
  int tid = threadIdx.x;
  int n = blockIdx.x * 256 + tid;
  int mbase = blockIdx.y * 16;
  if (tid < 64) {
    float4 a = ((const float4*)(t + (size_t)mbase * 16))[tid];
    float4 b = ((const float4*)(t + (size_t)TOKENS * 16 + (size_t)mbase * 16))[tid];
    ((float4*)tS)[tid] = make_float4(a.x + b.x, a.y + b.y, a.z + b.z, a.w + b.w);
  }
  const float4* lbp = (const float4*)(lb + (size_t)n * 16);
  float4 b0 = lbp[0], b1 = lbp[1], b2 = lbp[2], b3 = lbp[3];
  float bv = bias[n];
  __syncthreads();
#pragma unroll
  for (int mm = 0; mm < 16; ++mm) {
    const float* tr = &tS[mm * 16];
    float a = bv;
    a += tr[0] * b0.x + tr[1] * b0.y + tr[2] * b0.z + tr[3] * b0.w;
    a += tr[4] * b1.x + tr[5] * b1.y + tr[6] * b1.z + tr[7] * b1.w;
    a += tr[8] * b2.x + tr[9] * b2.y + tr[10] * b2.z + tr[11] * b2.w;
    a += tr[12] * b3.x + tr[13] * b3.y + tr[14] * b3.z + tr[15] * b3.w;
    out[(size_t)(mbase + mm) * OUT_F + n] = a;
  }
}

// ---------------------------------------------------------------------------
// finish (partial path): out = bias + lora + sum_kz partials. No atomics.
// ---------------------------------------------------------------------------
__global__ __launch_bounds__(256) void finish(const float* __restrict__ t,
                                              const float* __restrict__ lb,
                                              const float* __restrict__ bias,
                                              const float* __restrict__ part,
                                              float* __restrict__ out) {
  __shared__ float tS[16 * 16];
  int tid = threadIdx.x;
  int n = blockIdx.x * 256 + tid;
  int mbase = blockIdx.y * 16;
  if (tid < 64) {
    float4 a = ((const float4*)(t + (size_t)mbase * 16))[tid];
    float4 b = ((const float4*)(t + (size_t)TOKENS * 16 + (size_t)mbase * 16))[tid];
    ((float4*)tS)[tid] = make_float4(a.x + b.x, a.y + b.y, a.z + b.z, a.w + b.w);
  }
  const float4* lbp = (const float4*)(lb + (size_t)n * 16);
  float4 b0 = lbp[0], b1 = lbp[1], b2 = lbp[2], b3 = lbp[3];
  float bv = bias[n];
  __syncthreads();
#pragma unroll
  for (int mm = 0; mm < 16; ++mm) {
    const float* tr = &tS[mm * 16];
    float a = bv;
    a += tr[0] * b0.x + tr[1] * b0.y + tr[2] * b0.z + tr[3] * b0.w;
    a += tr[4] * b1.x + tr[5] * b1.y + tr[6] * b1.z + tr[7] * b1.w;
    a += tr[8] * b2.x + tr[9] * b2.y + tr[10] * b2.z + tr[11] * b2.w;
    a += tr[12] * b3.x + tr[13] * b3.y + tr[14] * b3.z + tr[15] * b3.w;
    size_t base = (size_t)(mbase + mm) * OUT_F + n;
#pragma unroll
    for (int kz = 0; kz < SPLITK; ++kz)
      a += part[(size_t)kz * TOKENS * OUT_F + base];
    out[base] = a;
  }
}

// ---------------------------------------------------------------------------
// gemm_q2: fused 2-bit-dequant f16 MFMA GEMM, split-K=8.
// R6: LDS-instruction-throughput was the R5 bottleneck (110K LDS-cyc/CU =
// ~73% busy; occupancy doubling changed nothing). Changes:
//  - back to 64x64 wave tiles (4 waves, 256 thr): 64 frag reads/block-iter
//    (min read amplification) instead of 96.
//  - A staged by global_load_lds (16B) straight into a DOUBLE-BUFFERED As:
//    zero A ds_write instrs, zero A prefetch VGPRs. Swizzle lives on the
//    global source address; LDS dest is lane-linear (m104/m173 rules).
//  - barrier #2 is raw s_barrier + lgkmcnt(0) only: the kt+1 A-DMA and B
//    loads stay in flight across it and drain at the NEXT iter's
//    __syncthreads (a full MFMA phase of slack ~1000cy > HBM ~900cy).
//    In-flight DMA targets the buffer nobody reads until after that drain.
//  - SPLITK=8 -> grid 1024 -> 3 blocks/CU (LDS 50KiB: 2x16K As + 16K Bs +
//    2K lut), __launch_bounds__(256,3) caps regs at 170 (working set ~130,
//    no spill). 12 waves/CU and half the barriers per block.
// Expected: ~74K LDS-cyc/CU (-33%), gemm ~42-48 us.
// ---------------------------------------------------------------------------
__global__ __launch_bounds__(256, 3) void gemm_q2(const u16* __restrict__ xb,
                                                  const int* __restrict__ wq,
                                                  const __half* __restrict__ wn,
                                                  float* __restrict__ dst,
                                                  int mode) {
  __shared__ __align__(16) u16 As[2][128 * 64];  // 2 x 16 KiB, DMA-filled
  __shared__ __align__(16) u16 Bs[128 * 64];     // 16 KiB
  __shared__ uint2 lut[256];

  int tid = threadIdx.x;
  int n0 = blockIdx.x * 128;
  int m0 = blockIdx.y * 128;
  int kz = blockIdx.z;
  int kbase = kz * KSPAN;

  {  // dequant LUT: byte -> 4 f16 unit values {-1,-1/3,1/3,1}
    int b = tid;
    float v0 = (float)(b & 3) * (2.f / 3.f) - 1.f;
    float v1 = (float)((b >> 2) & 3) * (2.f / 3.f) - 1.f;
    float v2 = (float)((b >> 4) & 3) * (2.f / 3.f) - 1.f;
    float v3 = (float)((b >> 6) & 3) * (2.f / 3.f) - 1.f;
    u32 lo = __builtin_bit_cast(u32, __float22half2_rn(make_float2(v0, v1)));
    u32 hi = __builtin_bit_cast(u32, __float22half2_rn(make_float2(v2, v3)));
    lut[b] = make_uint2(lo, hi);
  }

  int wave = tid >> 6, lane = tid & 63;
  int quad = lane >> 4, l15 = lane & 15;
  int mo = (wave & 1) * 64, no = (wave >> 1) * 64;

  // A staging: 1024 16B-chunks, 4 per thread, slot = tid + i*256 (lane-linear
  // within each wave, as global_load_lds requires). Source column is the
  // swizzled one: cl = c ^ (mm&7). Note (s+256)>>3 changes mm by 32, which
  // preserves mm&7, so all 4 chunks share the same swizzle offset.
  int aslot[4];
  const u16* ag[4];
#pragma unroll
  for (int i = 0; i < 4; ++i) {
    int s = tid + i * 256;
    int mm = s >> 3, c = s & 7;
    int cl = c ^ (mm & 7);
    aslot[i] = s;
    ag[i] = xb + (size_t)(m0 + mm) * IN_F + kbase + cl * 8;
  }

  // B staging: thread -> (row n, half h): 32 consecutive k (32 bytes).
  // wq byte address == flat weight index (each int32 = 1 code byte = 4 wts).
  int bn = tid >> 1, h = tid & 1;
  const char* gB = (const char*)wq + (size_t)(n0 + bn) * IN_F + kbase + h * 32;
  const __half* wnp = wn + (size_t)(n0 + bn) * 64 + kz * (KSPAN / 128);

  f32x4 zero4 = {0.f, 0.f, 0.f, 0.f};
  f32x4 acc[4][4];
#pragma unroll
  for (int i = 0; i < 4; ++i)
#pragma unroll
    for (int j = 0; j < 4; ++j) acc[i][j] = zero4;

  // prologue: DMA A(0) into As[0]; load B(0) code bytes + norm into regs
#pragma unroll
  for (int i = 0; i < 4; ++i) GLOAD16(ag[i], &((uint4*)As[0])[aslot[i]]);
  int4 pb0 = *(const int4*)(gB);
  int4 pb1 = *(const int4*)(gB + 16);
  __half pn = wnp[0];
  int cur = 0;

#pragma unroll 1
  for (int kt = 0; kt < KT; ++kt) {
    // barrier #1: full drain (vmcnt(0) included by __syncthreads) -- this is
    // where A-DMA(kt), pb(kt) land, after a whole compute phase of slack.
    // Also: prev iter's readers of Bs / As[cur^1] are done.
    __syncthreads();

    // ---- dequant + store B(kt) ----
    {
      __half2 nh = __half2half2(pn);
      int vv[8] = {pb0.x, pb0.y, pb0.z, pb0.w, pb1.x, pb1.y, pb1.z, pb1.w};
      u32 uu[16];
#pragma unroll
      for (int e = 0; e < 8; ++e) {
        uint2 lv = lut[vv[e] & 255];
        uu[2 * e] = hm2(lv.x, nh);
        uu[2 * e + 1] = hm2(lv.y, nh);
      }
      uint4* Bw = (uint4*)Bs;
#pragma unroll
      for (int cc = 0; cc < 4; ++cc) {
        int pc = (h * 4 + cc) ^ (bn & 7);
        Bw[bn * 8 + pc] = make_uint4(uu[4 * cc], uu[4 * cc + 1], uu[4 * cc + 2], uu[4 * cc + 3]);
      }
    }

    // ---- issue kt+1 staging: A-DMA into the other buffer, B into regs ----
    if (kt < KT - 1) {
      int ko = (kt + 1) * 64;  // 64 u16 == 64 weights == 64 wq bytes
#pragma unroll
      for (int i = 0; i < 4; ++i)
        GLOAD16(ag[i] + ko, &((uint4*)As[cur ^ 1])[aslot[i]]);
      pb0 = *(const int4*)(gB + ko);
      pb1 = *(const int4*)(gB + ko + 16);
      pn = wnp[(kt + 1) >> 1];
    }

    // barrier #2: only drain LDS writes (Bs). The just-issued A-DMA / B
    // global loads stay in flight across the barrier (they target As[cur^1]
    // and registers, which nothing reads before the next __syncthreads).
    asm volatile("s_waitcnt lgkmcnt(0)" ::: "memory");
    __builtin_amdgcn_s_barrier();
    asm volatile("" ::: "memory");

    // ---- compute: 2 k-substeps x (4+4 frags, 16 MFMAs) ----
    const uint4* Ar = (const uint4*)As[cur];
#pragma unroll
    for (int ks = 0; ks < 2; ++ks) {
      f16x8 af[4], bf[4];
#pragma unroll
      for (int mt = 0; mt < 4; ++mt) {
        int row = mo + mt * 16 + l15;
        int pc = (ks * 4 + quad) ^ (row & 7);
        af[mt] = __builtin_bit_cast(f16x8, Ar[row * 8 + pc]);
      }
#pragma unroll
      for (int nt = 0; nt < 4; ++nt) {
        int row = no + nt * 16 + l15;
        int pc = (ks * 4 + quad) ^ (row & 7);
        bf[nt] = __builtin_bit_cast(f16x8, ((const uint4*)Bs)[row * 8 + pc]);
      }
#pragma unroll
      for (int mt = 0; mt < 4; ++mt)
#pragma unroll
        for (int nt = 0; nt < 4; ++nt)
          acc[mt][nt] = __builtin_amdgcn_mfma_f32_16x16x32_f16(af[mt], bf[nt], acc[mt][nt], 0, 0, 0);
    }
    cur ^= 1;
  }

  // ---- epilogue ----
  // C/D layout: row m = quad*4 + reg, col n = lane&15  [m89/m91 verified]
  if (mode) {
    float* pp = dst + (size_t)kz * TOKENS * OUT_F;
#pragma unroll
    for (int mt = 0; mt < 4; ++mt)
#pragma unroll
      for (int nt = 0; nt < 4; ++nt)
#pragma unroll
        for (int r = 0; r < 4; ++r) {
          int mm = m0 + mo + mt * 16 + quad * 4 + r;
          int nn = n0 + no + nt * 16 + l15;
          pp[(size_t)mm * OUT_F + nn] = acc[mt][nt][r];
        }
  } else {
#pragma unroll
    for (int mt = 0; mt < 4; ++mt)
#pragma unroll
      for (int nt = 0; nt < 4; ++nt)
#pragma unroll
        for (int r = 0; r < 4; ++r) {
          int mm = m0 + mo + mt * 16 + quad * 4 + r;
          int nn = n0 + no + nt * 16 + l15;
          atomicAdd(&dst[(size_t)mm * OUT_F + nn], acc[mt][nt][r]);
        }
  }
}

extern "C" void kernel_launch(void* const* d_in, const int* in_sizes, int n_in,
                              void* d_out, int out_size, void* d_ws, size_t ws_size,
                              hipStream_t stream) {
  (void)in_sizes; (void)n_in; (void)out_size;
  const float* x = (const float*)d_in[0];
  const int* wq = (const int*)d_in[1];
  const void* wn_raw = d_in[2];
  const float* bias = (const float*)d_in[3];
  const float* la = (const float*)d_in[4];
  const float* lb = (const float*)d_in[5];
  float* out = (float*)d_out;

  u16* xb = (u16*)((char*)d_ws + XB_OFF);
  float* t = (float*)((char*)d_ws + T_OFF);
  __half* nf = (__half*)((char*)d_ws + NF_OFF);
  float* part = (float*)((char*)d_ws + PART_OFF);
  int usep = ws_size >= WS_NEED;  // constant per deployment -> graph-safe

  prep<<<1024, 256, 0, stream>>>(wn_raw, nf, x, la, xb, t);
  if (usep) {
    gemm_q2<<<dim3(OUT_F / 128, TOKENS / 128, SPLITK), 256, 0, stream>>>(xb, wq, nf, part, 1);
    finish<<<dim3(OUT_F / 256, TOKENS / 16), 256, 0, stream>>>(t, lb, bias, part, out);
  } else {
    prep2<<<dim3(OUT_F / 256, TOKENS / 16), 256, 0, stream>>>(t, lb, bias, out);
    gemm_q2<<<dim3(OUT_F / 128, TOKENS / 128, SPLITK), 256, 0, stream>>>(xb, wq, nf, out, 0);
  }
}